// Round 7
// baseline (2159.856 us; speedup 1.0000x reference)
//
#include <hip/hip_runtime.h>
#include <stdint.h>

#define TN_D 1024
#define TN_F 1024
#define SENT32 0xAAAAAAAAu
#define NBLK 64
#define CPB 16  // columns per block (1 per wave, 16 waves)

typedef _Float16 half4_t __attribute__((ext_vector_type(4)));

// ---------------------------------------------------------------------------
// Transpose + convert: core[s][i][j] f32 -> coreT[s][j][i] f16.
// ---------------------------------------------------------------------------
__global__ __launch_bounds__(256) void tn_transpose(const float* __restrict__ core,
                                                    _Float16* __restrict__ coreT) {
    __shared__ float tile[64][65];
    const int s = blockIdx.z;
    const size_t base = (size_t)s * TN_D * TN_D;
    const int j0 = blockIdx.x * 64;
    const int i0 = blockIdx.y * 64;
    const int tx = threadIdx.x;
    const int ty = threadIdx.y;
#pragma unroll
    for (int r = 0; r < 4; ++r) {
        const int ii = ty + 16 * r;
        const float4 v = *(const float4*)&core[base + (size_t)(i0 + ii) * TN_D + j0 + 4 * tx];
        tile[ii][4 * tx + 0] = v.x; tile[ii][4 * tx + 1] = v.y;
        tile[ii][4 * tx + 2] = v.z; tile[ii][4 * tx + 3] = v.w;
    }
    __syncthreads();
#pragma unroll
    for (int r = 0; r < 4; ++r) {
        const int jj = ty + 16 * r;
        _Float16 h4[4];
        h4[0] = (_Float16)tile[4 * tx + 0][jj];
        h4[1] = (_Float16)tile[4 * tx + 1][jj];
        h4[2] = (_Float16)tile[4 * tx + 2][jj];
        h4[3] = (_Float16)tile[4 * tx + 3][jj];
        *(uint64_t*)&coreT[base + (size_t)(j0 + jj) * TN_D + i0 + 4 * tx] = *(uint64_t*)h4;
    }
}

__device__ __forceinline__ float poll1(const uint32_t* p) {
    uint32_t u = __hip_atomic_load(p, __ATOMIC_RELAXED, __HIP_MEMORY_SCOPE_AGENT);
    while (u == SENT32)
        u = __hip_atomic_load(p, __ATOMIC_RELAXED, __HIP_MEMORY_SCOPE_AGENT);
    return __uint_as_float(u);
}

__device__ __forceinline__ float dot4h(float4 v, half4_t m) {
    return v.x * (float)m[0] + v.y * (float)m[1] + v.z * (float)m[2] + v.w * (float)m[3];
}

// ---------------------------------------------------------------------------
// Persistent chain, f16 matrix. 64 blocks x 1024 threads (16 waves); wave w
// owns column j = 16*blk + w.
// Per step: ONLY waves 12..15 (256 threads) poll the previous v-row — two
// independent 8B agent loads each (32K messages/sweep chip-wide, 8B-atomic
// arrival) — and stage it to LDS. One barrier. Every wave dots its
// register-prefetched f16 column (conflict-free 16B-stride LDS reads) vs v,
// deposits lane0 result in sentinel-guarded volatile LDS; wave 0 lanes 0..7
// gather pairs and publish 8B coalesced agent-stores (8 per block).
// Cross-block sync via 0xAA sentinel dataflow (relaxed agent atomics).
// ---------------------------------------------------------------------------
__global__ __launch_bounds__(1024, 1) void tn_chain_f16(const int* __restrict__ x,
                                                        const _Float16* __restrict__ mat,
                                                        const float* __restrict__ left,
                                                        const float* __restrict__ right,
                                                        float* __restrict__ vg,
                                                        float* __restrict__ out) {
    __shared__ float lv[2][TN_D];           // 8 KB double-buffered v
    __shared__ int xs[TN_F];                // 4 KB symbol stream
    volatile __shared__ uint32_t redv[CPB]; // per-wave results, sentinel-guarded
    __shared__ float red2[CPB];

    const int tid = threadIdx.x;
    const int w = tid >> 6;
    const int l = tid & 63;
    const int j = blockIdx.x * CPB + w;

    xs[tid] = x[tid];
    if (tid < CPB) redv[tid] = SENT32;
    __syncthreads();

    half4_t A0, A1, A2, A3, B0, B1, B2, B3;
    {
        const _Float16* cp = mat + ((size_t)xs[0] * TN_D + j) * TN_D;
        A0 = *(const half4_t*)(cp + 4 * l);
        A1 = *(const half4_t*)(cp + 4 * l + 256);
        A2 = *(const half4_t*)(cp + 4 * l + 512);
        A3 = *(const half4_t*)(cp + 4 * l + 768);
    }

#define STAGE_ROW(buf, row)                                                              \
    do {                                                                                 \
        if (tid >= 768) {                                                                \
            const int p = tid - 768;                                                     \
            const unsigned long long* bp =                                               \
                (const unsigned long long*)(vg + (size_t)(row) * TN_D);                  \
            unsigned long long u0 = __hip_atomic_load(bp + 2 * p, __ATOMIC_RELAXED,      \
                                                      __HIP_MEMORY_SCOPE_AGENT);         \
            unsigned long long u1 = __hip_atomic_load(bp + 2 * p + 1, __ATOMIC_RELAXED,  \
                                                      __HIP_MEMORY_SCOPE_AGENT);         \
            while ((uint32_t)u0 == SENT32)                                               \
                u0 = __hip_atomic_load(bp + 2 * p, __ATOMIC_RELAXED,                     \
                                       __HIP_MEMORY_SCOPE_AGENT);                        \
            while ((uint32_t)u1 == SENT32)                                               \
                u1 = __hip_atomic_load(bp + 2 * p + 1, __ATOMIC_RELAXED,                 \
                                       __HIP_MEMORY_SCOPE_AGENT);                        \
            unsigned long long* d = (unsigned long long*)lv[buf];                        \
            d[2 * p] = u0;                                                               \
            d[2 * p + 1] = u1;                                                           \
        }                                                                                \
    } while (0)

#define COMPUTE_PUBLISH(buf, row, R0, R1, R2, R3)                                        \
    do {                                                                                 \
        const float4* vv = (const float4*)lv[buf];                                       \
        float acc = dot4h(vv[l], R0) + dot4h(vv[l + 64], R1) +                           \
                    dot4h(vv[l + 128], R2) + dot4h(vv[l + 192], R3);                     \
        _Pragma("unroll")                                                                \
        for (int off = 32; off; off >>= 1) acc += __shfl_down(acc, off, 64);             \
        if (l == 0) {                                                                    \
            __asm__ volatile("" ::: "memory");                                           \
            redv[w] = __float_as_uint(acc);                                              \
        }                                                                                \
        if (w == 0 && l < 8) {                                                           \
            uint32_t a = redv[2 * l];                                                    \
            while (a == SENT32) a = redv[2 * l];                                         \
            uint32_t b = redv[2 * l + 1];                                                \
            while (b == SENT32) b = redv[2 * l + 1];                                     \
            redv[2 * l] = SENT32;                                                        \
            redv[2 * l + 1] = SENT32;                                                    \
            __asm__ volatile("" ::: "memory");                                           \
            const unsigned long long pk =                                                \
                (unsigned long long)a | ((unsigned long long)b << 32);                   \
            __hip_atomic_store(                                                          \
                (unsigned long long*)(vg + (size_t)(row) * TN_D) + 8 * blockIdx.x + l,   \
                pk, __ATOMIC_RELAXED, __HIP_MEMORY_SCOPE_AGENT);                         \
        }                                                                                \
    } while (0)

    for (int t = 0; t < TN_F; t += 2) {
        const int s1 = xs[(t + 1 < TN_F) ? t + 1 : TN_F - 1];
        const int s2 = xs[(t + 2 < TN_F) ? t + 2 : TN_F - 1];

        // ================= even step t (registers A) =================
        if (t == 0) {
            if (tid < 256) ((float4*)lv[0])[tid] = ((const float4*)left)[tid];
        } else {
            STAGE_ROW(0, t - 1);
        }
        __syncthreads();
        {   // prefetch col for t+1 (drains only at the NEXT barrier, a step away)
            const _Float16* cp = mat + ((size_t)s1 * TN_D + j) * TN_D;
            B0 = *(const half4_t*)(cp + 4 * l);
            B1 = *(const half4_t*)(cp + 4 * l + 256);
            B2 = *(const half4_t*)(cp + 4 * l + 512);
            B3 = *(const half4_t*)(cp + 4 * l + 768);
        }
        COMPUTE_PUBLISH(0, t, A0, A1, A2, A3);

        // ================= odd step t+1 (registers B) =================
        STAGE_ROW(1, t);
        __syncthreads();
        {   // prefetch col for t+2
            const _Float16* cp = mat + ((size_t)s2 * TN_D + j) * TN_D;
            A0 = *(const half4_t*)(cp + 4 * l);
            A1 = *(const half4_t*)(cp + 4 * l + 256);
            A2 = *(const half4_t*)(cp + 4 * l + 512);
            A3 = *(const half4_t*)(cp + 4 * l + 768);
        }
        COMPUTE_PUBLISH(1, t + 1, B0, B1, B2, B3);
    }

    // ---- final dot with right boundary: block 0 ----
    if (blockIdx.x == 0) {
        float v = poll1((const uint32_t*)vg + (size_t)(TN_F - 1) * TN_D + tid);
        float p = v * right[tid];
#pragma unroll
        for (int off = 32; off; off >>= 1) p += __shfl_down(p, off, 64);
        if (l == 0) red2[w] = p;
        __syncthreads();
        if (tid == 0) {
            float s = 0.f;
#pragma unroll
            for (int k = 0; k < CPB; ++k) s += red2[k];
            out[0] = s;
        }
    }
}

// ---------------------------------------------------------------------------
// Fallback (tiny workspace): R2-structure fp32, no transpose.
// ---------------------------------------------------------------------------
__device__ __forceinline__ float4 poll4(const uint32_t* vp) {
    const unsigned long long* p = (const unsigned long long*)vp;
    unsigned long long a = __hip_atomic_load(p, __ATOMIC_RELAXED, __HIP_MEMORY_SCOPE_AGENT);
    unsigned long long b = __hip_atomic_load(p + 1, __ATOMIC_RELAXED, __HIP_MEMORY_SCOPE_AGENT);
    while ((uint32_t)a == SENT32 || (uint32_t)(a >> 32) == SENT32)
        a = __hip_atomic_load(p, __ATOMIC_RELAXED, __HIP_MEMORY_SCOPE_AGENT);
    while ((uint32_t)b == SENT32 || (uint32_t)(b >> 32) == SENT32)
        b = __hip_atomic_load(p + 1, __ATOMIC_RELAXED, __HIP_MEMORY_SCOPE_AGENT);
    return make_float4(__uint_as_float((uint32_t)a), __uint_as_float((uint32_t)(a >> 32)),
                       __uint_as_float((uint32_t)b), __uint_as_float((uint32_t)(b >> 32)));
}

__global__ __launch_bounds__(256, 1) void tn_chain_f32(const int* __restrict__ x,
                                                       const float* __restrict__ mat,
                                                       const float* __restrict__ left,
                                                       const float* __restrict__ right,
                                                       float* __restrict__ vg,
                                                       float* __restrict__ out) {
    __shared__ float4 lv[2][TN_D / 4];
    __shared__ float red[4];
    const int tid = threadIdx.x;
    const int w = tid >> 6;
    const int l = tid & 63;
    const int j = blockIdx.x * 4 + w;

    for (int t = 0; t < TN_F; ++t) {
        if (t == 0) lv[0][tid] = ((const float4*)left)[tid];
        else lv[t & 1][tid] = poll4((const uint32_t*)vg + (size_t)(t - 1) * TN_D + 4 * tid);
        __syncthreads();
        const float* mp = mat + (size_t)x[t] * TN_D * TN_D + j;
        const float4* vv = lv[t & 1];
        float acc = 0.f;
#pragma unroll
        for (int k = 0; k < 4; ++k) {
            const int i = 4 * l + 256 * k;
            const float4 v = vv[l + 64 * k];
            acc += v.x * mp[(size_t)i * TN_D] + v.y * mp[(size_t)(i + 1) * TN_D] +
                   v.z * mp[(size_t)(i + 2) * TN_D] + v.w * mp[(size_t)(i + 3) * TN_D];
        }
#pragma unroll
        for (int off = 32; off; off >>= 1) acc += __shfl_down(acc, off, 64);
        if (l == 0)
            __hip_atomic_store((uint32_t*)vg + (size_t)t * TN_D + j, __float_as_uint(acc),
                               __ATOMIC_RELAXED, __HIP_MEMORY_SCOPE_AGENT);
    }
    if (blockIdx.x == 0) {
        float4 v = poll4((const uint32_t*)vg + (size_t)(TN_F - 1) * TN_D + 4 * tid);
        const float4 r4 = ((const float4*)right)[tid];
        float p = v.x * r4.x + v.y * r4.y + v.z * r4.z + v.w * r4.w;
#pragma unroll
        for (int off = 32; off; off >>= 1) p += __shfl_down(p, off, 64);
        if (l == 0) red[w] = p;
        __syncthreads();
        if (tid == 0) out[0] = red[0] + red[1] + red[2] + red[3];
    }
}

extern "C" void kernel_launch(void* const* d_in, const int* in_sizes, int n_in,
                              void* d_out, int out_size, void* d_ws, size_t ws_size,
                              hipStream_t stream) {
    const int* x = (const int*)d_in[0];
    const float* core = (const float*)d_in[1];
    const float* left = (const float*)d_in[2];
    const float* right = (const float*)d_in[3];
    float* out = (float*)d_out;

    const int nsym = in_sizes[1] / (TN_D * TN_D);
    const size_t coreTBytes = (size_t)in_sizes[1] * sizeof(_Float16);  // 64 MB
    const size_t vbufBytes = (size_t)TN_F * TN_D * sizeof(float);      // 4 MB

    if (ws_size >= coreTBytes + vbufBytes) {
        _Float16* coreT = (_Float16*)d_ws;
        float* vg = (float*)((char*)d_ws + coreTBytes);
        hipMemsetAsync(vg, 0xAA, vbufBytes, stream);
        tn_transpose<<<dim3(16, 16, nsym), dim3(16, 16), 0, stream>>>(core, coreT);
        tn_chain_f16<<<NBLK, 1024, 0, stream>>>(x, coreT, left, right, vg, out);
    } else {
        float* vg = (float*)d_ws;
        hipMemsetAsync(vg, 0xAA, vbufBytes, stream);
        tn_chain_f32<<<256, 256, 0, stream>>>(x, core, left, right, vg, out);
    }
}